// Round 1
// baseline (808.662 us; speedup 1.0000x reference)
//
#include <hip/hip_runtime.h>
#include <hip/hip_bf16.h>
#include <cstdint>

typedef __attribute__((ext_vector_type(8))) __bf16 bf16x8;
typedef __attribute__((ext_vector_type(4))) float f32x4;
typedef unsigned short u16;

#define CIN   512
#define E_OUT 256
#define HW    10000
#define NB    16
#define WID   100
#define LDB   40   // Bs row stride in bf16 elems (80B) -> conflict-free reads/writes

// ---------------- prep kernels ----------------

__global__ void k_convert_w(const float* __restrict__ conv_w, u16* __restrict__ wb) {
    int i = (blockIdx.x * 256 + threadIdx.x) * 4;  // 128 blocks * 256 * 4 = 131072
    float4 v = *(const float4*)(conv_w + i);
    __hip_bfloat162 p0 = __float22bfloat162_rn(make_float2(v.x, v.y));
    __hip_bfloat162 p1 = __float22bfloat162_rn(make_float2(v.z, v.w));
    uint2 o;
    o.x = *reinterpret_cast<unsigned*>(&p0);
    o.y = *reinterpret_cast<unsigned*>(&p1);
    *(uint2*)(wb + i) = o;
}

__global__ void k_wbar(const float* __restrict__ conv_w, double* __restrict__ wbar) {
    int c = blockIdx.x * 256 + threadIdx.x;  // 2 blocks -> c in [0,512)
    double s = 0.0;
    for (int e = 0; e < E_OUT; ++e) s += (double)conv_w[e * CIN + c];
    wbar[c] = s * (1.0 / 256.0);
}

__global__ void k_text(const float* __restrict__ text_emb, const float* __restrict__ text_w,
                       const float* __restrict__ text_b, float* __restrict__ out2) {
    int lane = threadIdx.x & 63;
    int e = blockIdx.x * 4 + (threadIdx.x >> 6);   // 64 blocks * 4 waves = 256 e's
    float s = 0.f;
    for (int i = lane; i < 786; i += 64) s = fmaf(text_w[e * 786 + i], text_emb[i], s);
#pragma unroll
    for (int off = 32; off >= 1; off >>= 1) s += __shfl_down(s, off);
    if (lane == 0) {
        float v = s + text_b[e];
        for (int b = 0; b < NB; ++b) out2[b * E_OUT + e] = v;
    }
}

// ---------------- main GEMM (src) + fused fp64 scores ----------------
// C[b][e][n] = sum_k conv_w[e][k] * feat[b][k][n] + conv_b[e]
// 128x128 tile, BK=32, mfma_f32_16x16x32_bf16, 4 waves as 2(m)x2(n), 4x4 subtiles each.

__global__ __launch_bounds__(256)
void k_gemm(const float* __restrict__ feat, const u16* __restrict__ Abf,
            const float* __restrict__ conv_b, const double* __restrict__ wbar,
            float* __restrict__ out0, double* __restrict__ scores) {
    __shared__ __attribute__((aligned(16))) u16 As[128 * 32];   // 8 KB, row = 32 bf16
    __shared__ __attribute__((aligned(16))) u16 Bs[128 * LDB];  // 10 KB, row = 40 bf16 (transposed feat)

    const int t    = threadIdx.x;
    const int lane = t & 63;
    const int w    = t >> 6;
    const int wm   = w & 1, wn = w >> 1;
    const int l16  = lane & 15, quad = lane >> 4;
    const int m0   = blockIdx.x * 128;
    const int n0   = blockIdx.y * 128;
    const int bb   = blockIdx.z;

    // staging assignments
    const int am = t >> 1;            // A row within tile
    const int ak = (t & 1) * 16;      // A col start (elems)
    const int bn = t & 127;           // B n within tile
    const int bk = (t >> 7) * 16;     // B k start (0 or 16)
    int ng = n0 + bn; if (ng > HW - 1) ng = HW - 1;   // clamp; store-guarded later
    const float* fB = feat + (size_t)bb * CIN * HW + (size_t)bk * HW + ng;
    const u16*   Ag = Abf + (m0 + am) * CIN + ak;
    u16* AsW = &As[am * 32 + ak];
    u16* BsW = &Bs[bn * LDB + bk];
    const u16* AsR = &As[(wm * 64 + l16) * 32 + quad * 8];
    const u16* BsR = &Bs[(wn * 64 + l16) * LDB + quad * 8];

    f32x4 acc[4][4];
#pragma unroll
    for (int i = 0; i < 4; ++i)
#pragma unroll
        for (int j = 0; j < 4; ++j) acc[i][j] = (f32x4){0.f, 0.f, 0.f, 0.f};

    double sc = 0.0;
    const bool doScore = (m0 == 0);   // block-uniform

    for (int ks = 0; ks < 16; ++ks) {
        const int k0 = ks * 32;
        // A stage: 32B of pre-converted bf16 conv_w
        uint4 a0 = *(const uint4*)(Ag + k0);
        uint4 a1 = *(const uint4*)(Ag + k0 + 8);
        // B stage: 16 k-strided dwords (coalesced across lanes in n)
        float bv[16];
        const float* fp = fB + (size_t)k0 * HW;
#pragma unroll
        for (int j = 0; j < 16; ++j) bv[j] = fp[(size_t)j * HW];
        if (doScore) {
#pragma unroll
            for (int j = 0; j < 16; ++j) sc = fma((double)bv[j], wbar[k0 + bk + j], sc);
        }
        unsigned pk[8];
#pragma unroll
        for (int j = 0; j < 8; ++j) {
            __hip_bfloat162 h = __float22bfloat162_rn(make_float2(bv[2 * j], bv[2 * j + 1]));
            pk[j] = *reinterpret_cast<unsigned*>(&h);
        }
        *(uint4*)AsW       = a0;
        *(uint4*)(AsW + 8) = a1;
        uint4 w0 = make_uint4(pk[0], pk[1], pk[2], pk[3]);
        uint4 w1 = make_uint4(pk[4], pk[5], pk[6], pk[7]);
        *(uint4*)BsW       = w0;
        *(uint4*)(BsW + 8) = w1;
        __syncthreads();

        bf16x8 af[4], bf[4];
#pragma unroll
        for (int ms = 0; ms < 4; ++ms) af[ms] = *(const bf16x8*)(AsR + ms * 16 * 32);
#pragma unroll
        for (int ns = 0; ns < 4; ++ns) bf[ns] = *(const bf16x8*)(BsR + ns * 16 * LDB);
#pragma unroll
        for (int ms = 0; ms < 4; ++ms)
#pragma unroll
            for (int ns = 0; ns < 4; ++ns)
                acc[ms][ns] = __builtin_amdgcn_mfma_f32_16x16x32_bf16(af[ms], bf[ns], acc[ms][ns], 0, 0, 0);
        __syncthreads();
    }

    // epilogue: C = acc + conv_b
#pragma unroll
    for (int ns = 0; ns < 4; ++ns) {
        int n = n0 + wn * 64 + ns * 16 + l16;
        if (n < HW) {
#pragma unroll
            for (int ms = 0; ms < 4; ++ms) {
                int e = m0 + wm * 64 + ms * 16 + quad * 4;
                float* op = out0 + ((size_t)bb * E_OUT + e) * HW + n;
#pragma unroll
                for (int r = 0; r < 4; ++r)
                    op[(size_t)r * HW] = acc[ms][ns][r] + conv_b[e + r];
            }
        }
    }

    // fused scores: thread t (khalf 0) + thread t+128 (khalf 1) cover all 512 k
    if (doScore) {
        double* scb = (double*)As;   // safe: all LDS reads drained by last barrier
        if (t >= 128) scb[t - 128] = sc;
        __syncthreads();
        if (t < 128) {
            int n = n0 + t;
            if (n < HW) scores[(size_t)bb * HW + n] = sc + scb[t];
        }
    }
}

// ---------------- exact top-K (desc value, tie -> lower idx) + pos_embed ----------------

struct KV { unsigned long long k; unsigned i; };  // i = ~idx
__device__ inline bool kv_gt(const KV& a, const KV& b) {
    return (a.k > b.k) || (a.k == b.k && a.i > b.i);
}
__device__ inline unsigned long long dkey(double v) {
    unsigned long long u = (unsigned long long)__double_as_longlong(v);
    return (u & 0x8000000000000000ull) ? ~u : (u | 0x8000000000000000ull);
}

__global__ __launch_bounds__(256)
void k_topk(double* __restrict__ scores, const float* __restrict__ coord_w,
            const float* __restrict__ coord_b, float* __restrict__ out1, int K) {
    __shared__ KV  wred[4];
    __shared__ int sel[128];
    const int b = blockIdx.x, t = threadIdx.x;
    const int lane = t & 63, w = t >> 6;
    double* sc = scores + (size_t)b * HW;

    // per-thread top-2 over strided entries p = t + 256*i
    KV a = {0, 0}, s2 = {0, 0};
    for (int i = 0; i < 40; ++i) {
        int p = t + 256 * i;
        if (p < HW) {
            KV c = {dkey(sc[p]), ~(unsigned)p};
            if (kv_gt(c, a)) { s2 = a; a = c; }
            else if (kv_gt(c, s2)) s2 = c;
        }
    }

    for (int k = 0; k < K; ++k) {
        KV v = a;
#pragma unroll
        for (int off = 32; off >= 1; off >>= 1) {
            KV o;
            o.k = __shfl_down(v.k, off);
            o.i = __shfl_down(v.i, off);
            if (kv_gt(o, v)) v = o;
        }
        if (lane == 0) wred[w] = v;
        __syncthreads();
        KV best = wred[0];
        for (int j = 1; j < 4; ++j) if (kv_gt(wred[j], best)) best = wred[j];
        int idx = (int)(~best.i);
        if (t == (idx & 255)) {           // owner: invalidate + promote/rescan
            sc[idx] = -1.0e308;
            if (s2.k != 0ull || s2.i != 0u) { a = s2; s2.k = 0; s2.i = 0; }
            else {
                a.k = 0; a.i = 0;
                for (int i = 0; i < 40; ++i) {
                    int p = t + 256 * i;
                    if (p < HW) {
                        KV c = {dkey(sc[p]), ~(unsigned)p};
                        if (kv_gt(c, a)) { s2 = a; a = c; }
                        else if (kv_gt(c, s2)) s2 = c;
                    }
                }
            }
        }
        if (t == 0) sel[k] = idx;
        __syncthreads();
    }

    // pos_embed: thread t = e channel
    float cw0 = coord_w[t * 2], cw1 = coord_w[t * 2 + 1], cb2 = coord_b[t];
    for (int k = 0; k < K; ++k) {
        int idx = sel[k];
        float xs = (float)(idx % WID) / 100.0f;
        float ys = (float)(idx / WID) / 100.0f;
        out1[((size_t)b * K + k) * E_OUT + t] = fmaf(xs, cw0, fmaf(ys, cw1, cb2));
    }
}

// ---------------- launcher ----------------

extern "C" void kernel_launch(void* const* d_in, const int* in_sizes, int n_in,
                              void* d_out, int out_size, void* d_ws, size_t ws_size,
                              hipStream_t stream) {
    const float* feat     = (const float*)d_in[0];
    // d_in[1] = mask (unused by reference)
    const float* text_emb = (const float*)d_in[2];
    const float* conv_w   = (const float*)d_in[3];
    const float* conv_b   = (const float*)d_in[4];
    const float* text_w   = (const float*)d_in[5];
    const float* text_b   = (const float*)d_in[6];
    const float* coord_w  = (const float*)d_in[7];
    const float* coord_b  = (const float*)d_in[8];

    // K from out_size: out = [16*256*10000] + [16*K*256] + [16*256]
    long long rem = (long long)out_size - (long long)NB * E_OUT * HW - (long long)NB * E_OUT;
    int K = (int)(rem / ((long long)NB * E_OUT));
    if (K < 1 || K > 128) K = 100;

    float* out0 = (float*)d_out;
    float* out1 = out0 + (size_t)NB * E_OUT * HW;
    float* out2 = out1 + (size_t)NB * K * E_OUT;

    char* ws = (char*)d_ws;
    u16*    Abf    = (u16*)ws;                        // 262144 B  (conv_w in bf16)
    double* wbar   = (double*)(ws + 262144);          // 4096 B
    double* scores = (double*)(ws + 262144 + 4096);   // 1.28 MB

    k_convert_w<<<dim3(128), dim3(256), 0, stream>>>(conv_w, Abf);
    k_wbar<<<dim3(2), dim3(256), 0, stream>>>(conv_w, wbar);
    k_text<<<dim3(64), dim3(256), 0, stream>>>(text_emb, text_w, text_b, out2);
    k_gemm<<<dim3(2, 79, 16), dim3(256), 0, stream>>>(feat, Abf, conv_b, wbar, out0, scores);
    k_topk<<<dim3(16), dim3(256), 0, stream>>>(scores, coord_w, coord_b, out1, K);
}

// Round 2
// 639.616 us; speedup vs baseline: 1.2643x; 1.2643x over previous
//
#include <hip/hip_runtime.h>
#include <hip/hip_bf16.h>
#include <cstdint>

typedef __attribute__((ext_vector_type(8))) __bf16 bf16x8;
typedef __attribute__((ext_vector_type(4))) float f32x4;
typedef unsigned short u16;
typedef unsigned long long u64;

#define CIN   512
#define E_OUT 256
#define HW    10000
#define NB    16
#define WID   100
#define LDB   40   // Bs row stride in bf16 elems (80B) -> conflict-free (8-phase min)
#define NT    157  // ceil(10000/64) n-tiles

// ---------------- prep kernels ----------------

__global__ void k_convert_w(const float* __restrict__ conv_w, u16* __restrict__ wb) {
    int i = (blockIdx.x * 256 + threadIdx.x) * 4;  // 128 blocks
    float4 v = *(const float4*)(conv_w + i);
    __hip_bfloat162 p0 = __float22bfloat162_rn(make_float2(v.x, v.y));
    __hip_bfloat162 p1 = __float22bfloat162_rn(make_float2(v.z, v.w));
    uint2 o;
    o.x = *reinterpret_cast<unsigned*>(&p0);
    o.y = *reinterpret_cast<unsigned*>(&p1);
    *(uint2*)(wb + i) = o;
}

// wbar[c] = mean_e conv_w[e][c], fp64, deterministic tree
__global__ void k_wbar(const float* __restrict__ conv_w, double* __restrict__ wbar) {
    __shared__ double part[4][64];
    int t = threadIdx.x, lane = t & 63, w = t >> 6;
    int c = blockIdx.x * 64 + lane;                    // 8 blocks
    const float* p = conv_w + (size_t)(w * 64) * CIN + c;
    double s0 = 0, s1 = 0, s2 = 0, s3 = 0;
    for (int e = 0; e < 64; e += 4) {
        s0 += (double)p[(size_t)(e + 0) * CIN];
        s1 += (double)p[(size_t)(e + 1) * CIN];
        s2 += (double)p[(size_t)(e + 2) * CIN];
        s3 += (double)p[(size_t)(e + 3) * CIN];
    }
    part[w][lane] = (s0 + s1) + (s2 + s3);
    __syncthreads();
    if (t < 64)
        wbar[blockIdx.x * 64 + t] =
            ((part[0][t] + part[1][t]) + (part[2][t] + part[3][t])) * (1.0 / 256.0);
}

__global__ void k_text(const float* __restrict__ text_emb, const float* __restrict__ text_w,
                       const float* __restrict__ text_b, float* __restrict__ out2) {
    int lane = threadIdx.x & 63;
    int e = blockIdx.x * 4 + (threadIdx.x >> 6);   // 64 blocks
    float s = 0.f;
    for (int i = lane; i < 786; i += 64) s = fmaf(text_w[e * 786 + i], text_emb[i], s);
#pragma unroll
    for (int off = 32; off >= 1; off >>= 1) s += __shfl_down(s, off);
    if (lane == 0) {
        float v = s + text_b[e];
        for (int b = 0; b < NB; ++b) out2[b * E_OUT + e] = v;
    }
}

// ---------------- main GEMM: M=256 full, N=64 tile, BK=32, dbuf B ----------------
// C[b][e][n] = sum_k conv_w[e][k]*feat[b][k][n] + conv_b[e]; fused fp64 scores.

__global__ __launch_bounds__(256)
void k_gemm(const float* __restrict__ feat, const u16* __restrict__ Abf,
            const float* __restrict__ conv_b, const double* __restrict__ wbar,
            float* __restrict__ out0, double* __restrict__ scores) {
    __shared__ __attribute__((aligned(16))) u16 Bs[2][64 * LDB];  // 2 x 5 KB
    __shared__ __attribute__((aligned(16))) double wbs[CIN];      // 4 KB
    __shared__ double scp[256];                                   // 2 KB

    const int t    = threadIdx.x;
    const int lane = t & 63, w = t >> 6;
    const int l16  = lane & 15, quad = lane >> 4;
    const int n0   = blockIdx.x * 64;
    const int bb   = blockIdx.y;

    // stage wbar to LDS (broadcast-read later; uniform per wave)
    ((uint4*)wbs)[t] = ((const uint4*)wbar)[t];

    // B staging: thread covers n=lane, k in [w*8, w*8+8) each K-step
    const int kb = w * 8;
    int ng = n0 + lane; if (ng > HW - 1) ng = HW - 1;      // clamp; stores guarded
    const float* fB = feat + (size_t)bb * CIN * HW + (size_t)kb * HW + ng;
    u16* BsW0 = &Bs[0][lane * LDB + kb];
    u16* BsW1 = &Bs[1][lane * LDB + kb];
    const u16* BsR0 = &Bs[0][l16 * LDB + quad * 8];
    const u16* BsR1 = &Bs[1][l16 * LDB + quad * 8];

    // A frags direct from global bf16 weights (L2-hot, 256 KB total)
    const u16* Ag = Abf + (size_t)(w * 64 + l16) * CIN + quad * 8;

    f32x4 acc[4][4];
#pragma unroll
    for (int i = 0; i < 4; ++i)
#pragma unroll
        for (int j = 0; j < 4; ++j) acc[i][j] = (f32x4){0.f, 0.f, 0.f, 0.f};

    // prologue loads for ks=0
    bf16x8 af[4];
    float bv[8];
#pragma unroll
    for (int ms = 0; ms < 4; ++ms) af[ms] = *(const bf16x8*)(Ag + ms * 16 * CIN);
#pragma unroll
    for (int j = 0; j < 8; ++j) bv[j] = fB[(size_t)j * HW];

    double sc = 0.0;
    __syncthreads();   // wbs ready

#pragma unroll
    for (int ks = 0; ks < 16; ++ks) {
        // fused fp64 score + bf16 pack (first use of bv -> waits its vmcnt)
#pragma unroll
        for (int j = 0; j < 8; ++j) sc = fma((double)bv[j], wbs[ks * 32 + kb + j], sc);
        unsigned pk[4];
#pragma unroll
        for (int j = 0; j < 4; ++j) {
            __hip_bfloat162 h = __float22bfloat162_rn(make_float2(bv[2 * j], bv[2 * j + 1]));
            pk[j] = *reinterpret_cast<unsigned*>(&h);
        }
        uint4 wv = make_uint4(pk[0], pk[1], pk[2], pk[3]);
        *(uint4*)((ks & 1) ? BsW1 : BsW0) = wv;
        __syncthreads();
        // prefetch ks+1 AFTER the barrier so it stays in flight across dsread+mfma
        bf16x8 afn[4];
        float bvn[8];
        if (ks < 15) {
#pragma unroll
            for (int ms = 0; ms < 4; ++ms)
                afn[ms] = *(const bf16x8*)(Ag + ms * 16 * CIN + (ks + 1) * 32);
            const float* fp = fB + (size_t)(ks + 1) * 32 * HW;
#pragma unroll
            for (int j = 0; j < 8; ++j) bvn[j] = fp[(size_t)j * HW];
        }
        const u16* br = (ks & 1) ? BsR1 : BsR0;
        bf16x8 bf[4];
#pragma unroll
        for (int ns = 0; ns < 4; ++ns) bf[ns] = *(const bf16x8*)(br + ns * 16 * LDB);
#pragma unroll
        for (int ms = 0; ms < 4; ++ms)
#pragma unroll
            for (int ns = 0; ns < 4; ++ns)
                acc[ms][ns] = __builtin_amdgcn_mfma_f32_16x16x32_bf16(af[ms], bf[ns], acc[ms][ns], 0, 0, 0);
        if (ks < 15) {
#pragma unroll
            for (int ms = 0; ms < 4; ++ms) af[ms] = afn[ms];
#pragma unroll
            for (int j = 0; j < 8; ++j) bv[j] = bvn[j];
        }
    }

    // epilogue: C = acc + conv_b
#pragma unroll
    for (int ns = 0; ns < 4; ++ns) {
        int n = n0 + ns * 16 + l16;
        if (n < HW) {
#pragma unroll
            for (int ms = 0; ms < 4; ++ms) {
                int e = w * 64 + ms * 16 + quad * 4;
                float4 cb4 = *(const float4*)(conv_b + e);
                float* op = out0 + ((size_t)bb * E_OUT + e) * HW + n;
                op[0]              = acc[ms][ns][0] + cb4.x;
                op[(size_t)1 * HW] = acc[ms][ns][1] + cb4.y;
                op[(size_t)2 * HW] = acc[ms][ns][2] + cb4.z;
                op[(size_t)3 * HW] = acc[ms][ns][3] + cb4.w;
            }
        }
    }

    // scores: 4 partials per n (one per wave), deterministic combine
    scp[t] = sc;
    __syncthreads();
    if (t < 64) {
        int n = n0 + t;
        if (n < HW)
            scores[(size_t)bb * HW + n] = (scp[t] + scp[t + 64]) + (scp[t + 128] + scp[t + 192]);
    }
}

// ---------------- top-K via 64-bit key bisection + exact tie handling ----------------

__device__ __forceinline__ u64 dkey(double v) {
    u64 u = (u64)__double_as_longlong(v);
    return (u & 0x8000000000000000ull) ? ~u : (u | 0x8000000000000000ull);
}

__device__ __forceinline__ int redcnt(int c, int lane, int w, int parity, int* cntbuf) {
#pragma unroll
    for (int off = 32; off >= 1; off >>= 1) c += __shfl_down(c, off);
    if (lane == 0) cntbuf[parity * 4 + w] = c;
    __syncthreads();
    return cntbuf[parity * 4 + 0] + cntbuf[parity * 4 + 1] +
           cntbuf[parity * 4 + 2] + cntbuf[parity * 4 + 3];
}

__global__ __launch_bounds__(256)
void k_topk(const double* __restrict__ scores, const float* __restrict__ coord_w,
            const float* __restrict__ coord_b, float* __restrict__ out1, int K) {
    __shared__ int cntbuf[8];
    __shared__ u64 skey[128];
    __shared__ unsigned sidx[128];
    __shared__ int scnt;
    const int b = blockIdx.x, t = threadIdx.x, lane = t & 63, w = t >> 6;
    const double* sc = scores + (size_t)b * HW;

    u64 key[40];
#pragma unroll
    for (int i = 0; i < 40; ++i) {
        int p = t + 256 * i;
        key[i] = (p < HW) ? dkey(sc[p]) : 0ull;   // finite scores -> dkey > 0
    }
    if (t == 0) scnt = 0;

    // bisection: T = largest x with count(key >= x) >= K  ==  Kth largest key
    int parity = 0;
    u64 T = 0ull;
    for (int bit = 63; bit >= 0; --bit) {
        u64 cand = T | (1ull << bit);
        int c = 0;
#pragma unroll
        for (int i = 0; i < 40; ++i) c += (key[i] >= cand) ? 1 : 0;
        int tot = redcnt(c, lane, w, parity, cntbuf); parity ^= 1;
        if (tot >= K) T = cand;
    }
    // strictly-greater count
    int c = 0;
#pragma unroll
    for (int i = 0; i < 40; ++i) c += (key[i] > T) ? 1 : 0;
    int Cgt = redcnt(c, lane, w, parity, cntbuf); parity ^= 1;
    int R = K - Cgt;   // >= 1 entries needed from ties, smallest indices first

    // lower-bound bisection on idx among key==T
    int lo = 0, hi = HW - 1;
    while (lo < hi) {   // uniform across block
        int mid = (lo + hi) >> 1;
        int cc = 0;
#pragma unroll
        for (int i = 0; i < 40; ++i) {
            int p = t + 256 * i;
            cc += (key[i] == T && p <= mid) ? 1 : 0;
        }
        int tot = redcnt(cc, lane, w, parity, cntbuf); parity ^= 1;
        if (tot >= R) hi = mid; else lo = mid + 1;
    }
    const int Xs = lo;

    // gather exactly K selected (order fixed by sort below)
#pragma unroll
    for (int i = 0; i < 40; ++i) {
        int p = t + 256 * i;
        if (key[i] > T || (key[i] == T && p <= Xs)) {
            int pos = atomicAdd(&scnt, 1);
            if (pos < 128) { skey[pos] = key[i]; sidx[pos] = (unsigned)p; }
        }
    }
    __syncthreads();
    if (t < 128 && t >= scnt) { skey[t] = 0ull; sidx[t] = 0xFFFFFFFFu; }
    __syncthreads();

    // bitonic sort of 128 slots, order: key desc, idx asc
    for (int kk = 2; kk <= 128; kk <<= 1) {
        for (int j = kk >> 1; j >= 1; j >>= 1) {
            if (t < 128) {
                int ix = t ^ j;
                if (ix > t) {
                    u64 ka = skey[t], kb2 = skey[ix];
                    unsigned ia = sidx[t], ib = sidx[ix];
                    bool beforeJI = (kb2 > ka) || (kb2 == ka && ib < ia);
                    bool beforeIJ = (ka > kb2) || (ka == kb2 && ia < ib);
                    bool up = ((t & kk) == 0);
                    bool ooo = up ? beforeJI : beforeIJ;
                    if (ooo) { skey[t] = kb2; sidx[t] = ib; skey[ix] = ka; sidx[ix] = ia; }
                }
            }
            __syncthreads();
        }
    }

    // pos_embed: thread t = e channel
    float cw0 = coord_w[2 * t], cw1 = coord_w[2 * t + 1], cb = coord_b[t];
    for (int k = 0; k < K; ++k) {
        int idx = (int)sidx[k];
        float xs = (float)(idx % WID) * (1.0f / 100.0f);
        float ys = (float)(idx / WID) * (1.0f / 100.0f);
        out1[((size_t)b * K + k) * E_OUT + t] = fmaf(xs, cw0, fmaf(ys, cw1, cb));
    }
}

// ---------------- launcher ----------------

extern "C" void kernel_launch(void* const* d_in, const int* in_sizes, int n_in,
                              void* d_out, int out_size, void* d_ws, size_t ws_size,
                              hipStream_t stream) {
    const float* feat     = (const float*)d_in[0];
    // d_in[1] = mask (unused)
    const float* text_emb = (const float*)d_in[2];
    const float* conv_w   = (const float*)d_in[3];
    const float* conv_b   = (const float*)d_in[4];
    const float* text_w   = (const float*)d_in[5];
    const float* text_b   = (const float*)d_in[6];
    const float* coord_w  = (const float*)d_in[7];
    const float* coord_b  = (const float*)d_in[8];

    long long rem = (long long)out_size - (long long)NB * E_OUT * HW - (long long)NB * E_OUT;
    int K = (int)(rem / ((long long)NB * E_OUT));
    if (K < 1 || K > 128) K = 100;

    float* out0 = (float*)d_out;
    float* out1 = out0 + (size_t)NB * E_OUT * HW;
    float* out2 = out1 + (size_t)NB * K * E_OUT;

    char* ws = (char*)d_ws;
    u16*    Abf    = (u16*)ws;                        // 262144 B
    double* wbar   = (double*)(ws + 262144);          // 4096 B
    double* scores = (double*)(ws + 262144 + 4096);   // 1.28 MB

    k_convert_w<<<dim3(128), dim3(256), 0, stream>>>(conv_w, Abf);
    k_wbar<<<dim3(8), dim3(256), 0, stream>>>(conv_w, wbar);
    k_text<<<dim3(64), dim3(256), 0, stream>>>(text_emb, text_w, text_b, out2);
    k_gemm<<<dim3(NT, NB), dim3(256), 0, stream>>>(feat, Abf, conv_b, wbar, out0, scores);
    k_topk<<<dim3(NB), dim3(256), 0, stream>>>(scores, coord_w, coord_b, out1, K);
}